// Round 1
// baseline (2181.230 us; speedup 1.0000x reference)
//
#include <hip/hip_runtime.h>
#include <hip/hip_bf16.h>
#include <stdint.h>
#include <math.h>

#define B_   4
#define L_   2048
#define DM   1024
#define DI   2048
#define NR   (B_*L_)   // 8192 rows
#define NST  64
#define NPAD 256       // padded x_proj rows (192 real)
#define LOG2E 1.44269504088896340736f

typedef __attribute__((ext_vector_type(8))) short bf16x8;
typedef __attribute__((ext_vector_type(4))) float f32x4;

__device__ __forceinline__ float bf2f(unsigned short u) {
  union { unsigned int i; float f; } v; v.i = ((unsigned int)u) << 16; return v.f;
}
__device__ __forceinline__ unsigned short f2bf(float f) {
  union { float f; unsigned int i; } v; v.f = f;
  unsigned int r = v.i + 0x7fff + ((v.i >> 16) & 1);
  return (unsigned short)(r >> 16);
}

__device__ __forceinline__ void gload_lds16(const void* g, void* l) {
  __builtin_amdgcn_global_load_lds(
      (const __attribute__((address_space(1))) void*)g,
      (__attribute__((address_space(3))) void*)l, 16, 0, 0);
}

// ---------- weight conversion ----------
__global__ __launch_bounds__(256) void cvt_k(const float* __restrict__ s,
                                             unsigned short* __restrict__ d, int nq) {
  int i = blockIdx.x * 256 + threadIdx.x;
  if (i < nq) {
    float4 v = ((const float4*)s)[i];
    ushort4 o;
    o.x = f2bf(v.x); o.y = f2bf(v.y); o.z = f2bf(v.z); o.w = f2bf(v.w);
    ((ushort4*)d)[i] = o;
  }
}

__global__ __launch_bounds__(256) void cvt_pad_xp(const float* __restrict__ s,
                                                  unsigned short* __restrict__ d) {
  int idx = blockIdx.x * 256 + threadIdx.x;   // over 256*2048
  int row = idx >> 11, col = idx & 2047;
  float v = (row < 192) ? s[row * 2048 + col] : 0.f;
  d[idx] = f2bf(v);
}

// ---------- RMSNorm (f32 in -> bf16 out) ----------
__global__ __launch_bounds__(256) void rmsnorm_k(const float* __restrict__ x,
                                                 const float* __restrict__ w,
                                                 unsigned short* __restrict__ xn) {
  int row = blockIdx.x;
  int t = threadIdx.x;
  float4 v = ((const float4*)(x + (size_t)row * DM))[t];
  float ss = v.x*v.x + v.y*v.y + v.z*v.z + v.w*v.w;
  #pragma unroll
  for (int m = 1; m < 64; m <<= 1) ss += __shfl_xor(ss, m, 64);
  __shared__ float s4[4];
  if ((t & 63) == 0) s4[t >> 6] = ss;
  __syncthreads();
  float tot = s4[0] + s4[1] + s4[2] + s4[3];
  float scale = rsqrtf(tot * (1.0f / DM) + 1e-6f);
  float4 wv = ((const float4*)w)[t];
  ushort4 o;
  o.x = f2bf(v.x * scale * wv.x);
  o.y = f2bf(v.y * scale * wv.y);
  o.z = f2bf(v.z * scale * wv.z);
  o.w = f2bf(v.w * scale * wv.w);
  ((ushort4*)(xn + (size_t)row * DM))[t] = o;
}

// ---------- bf16 MFMA GEMM: C[M,N] = A[M,K] * W[N,K]^T ----------
// EPI 0: bf16 store; 1: softplus(acc + aux[col]) bf16 store; 2: acc + auxF32[idx] f32 store
template<int EPI>
__global__ __launch_bounds__(256)
void gemm_bt(const unsigned short* __restrict__ A,
             const unsigned short* __restrict__ W,
             void* __restrict__ C, const float* __restrict__ aux,
             int M, int N, int K, int lda, int ldb, int ldc)
{
  __shared__ unsigned short lA[128 * 32];
  __shared__ unsigned short lB[128 * 32];
  const int tid = threadIdx.x;
  const int lane = tid & 63, w = tid >> 6;
  const int brow = blockIdx.y * 128, bcol = blockIdx.x * 128;
  const int wr = w >> 1, wc = w & 1;

  f32x4 acc[4][4];
  #pragma unroll
  for (int m = 0; m < 4; ++m)
    #pragma unroll
    for (int n = 0; n < 4; ++n) acc[m][n] = (f32x4){0.f, 0.f, 0.f, 0.f};

  // staging: wave w covers 32 rows; 2 insts of 16 rows; lane -> row (l>>2), col (l&3)*8
  const int srow = w * 32 + (lane >> 2);
  const int scol = (lane & 3) * 8;
  const unsigned short* gA = A + (size_t)(brow + srow) * lda + scol;
  const unsigned short* gB = W + (size_t)(bcol + srow) * ldb + scol;
  unsigned short* sA = lA + (w * 32) * 32;
  unsigned short* sB = lB + (w * 32) * 32;

  const int ka = (lane >> 4) * 8;
  const int ra = lane & 15;

  for (int k0 = 0; k0 < K; k0 += 32) {
    gload_lds16(gA + k0,                sA);
    gload_lds16(gA + k0 + 16 * lda,     sA + 16 * 32);
    gload_lds16(gB + k0,                sB);
    gload_lds16(gB + k0 + 16 * ldb,     sB + 16 * 32);
    __syncthreads();
    bf16x8 af[4], bfr[4];
    #pragma unroll
    for (int m = 0; m < 4; ++m)
      af[m] = *(const bf16x8*)(lA + (wr * 64 + m * 16 + ra) * 32 + ka);
    #pragma unroll
    for (int n = 0; n < 4; ++n)
      bfr[n] = *(const bf16x8*)(lB + (wc * 64 + n * 16 + ra) * 32 + ka);
    #pragma unroll
    for (int m = 0; m < 4; ++m)
      #pragma unroll
      for (int n = 0; n < 4; ++n)
        acc[m][n] = __builtin_amdgcn_mfma_f32_16x16x32_bf16(af[m], bfr[n], acc[m][n], 0, 0, 0);
    __syncthreads();
  }

  const int fq = lane >> 4;
  #pragma unroll
  for (int m = 0; m < 4; ++m) {
    #pragma unroll
    for (int n = 0; n < 4; ++n) {
      #pragma unroll
      for (int j = 0; j < 4; ++j) {
        int r = brow + wr * 64 + m * 16 + fq * 4 + j;
        int c = bcol + wc * 64 + n * 16 + ra;
        size_t idx = (size_t)r * ldc + c;
        float v = acc[m][n][j];
        if (EPI == 0) {
          ((unsigned short*)C)[idx] = f2bf(v);
        } else if (EPI == 1) {
          v += aux[c];
          v = (v > 20.f) ? v : log1pf(__expf(v));
          ((unsigned short*)C)[idx] = f2bf(v);
        } else {
          ((float*)C)[idx] = v + aux[idx];
        }
      }
    }
  }
}

// ---------- causal depthwise conv1d + SiLU ----------
// x_in = xz[:, 0:2048] (bf16, ld 4096); u bf16 [NR, 2048]
__global__ __launch_bounds__(256) void conv_silu_k(const unsigned short* __restrict__ xz,
                                                   const float* __restrict__ cw,
                                                   const float* __restrict__ cb,
                                                   unsigned short* __restrict__ u) {
  int d = blockIdx.x * 256 + threadIdx.x;   // 0..2047
  int b = blockIdx.z;
  int l0 = blockIdx.y * 128;
  float w0 = cw[d * 4 + 0], w1 = cw[d * 4 + 1], w2 = cw[d * 4 + 2], w3 = cw[d * 4 + 3];
  float bias = cb[d];
  float xm3 = 0.f, xm2 = 0.f, xm1 = 0.f;
  size_t rb = (size_t)b * L_;
  if (l0 > 0) {
    xm3 = bf2f(xz[(rb + l0 - 3) * 4096 + d]);
    xm2 = bf2f(xz[(rb + l0 - 2) * 4096 + d]);
    xm1 = bf2f(xz[(rb + l0 - 1) * 4096 + d]);
  }
  for (int l = l0; l < l0 + 128; ++l) {
    float xc = bf2f(xz[(rb + l) * 4096 + d]);
    float v = w0 * xm3 + w1 * xm2 + w2 * xm1 + w3 * xc + bias;
    float s = v / (1.f + __expf(-v));
    u[(rb + l) * 2048 + d] = f2bf(s);
    xm3 = xm2; xm2 = xm1; xm1 = xc;
  }
}

// ---------- selective scan + gate ----------
// wave owns d0=base+2w, d1=d0+1; lane = n. Sequential over L.
__global__ __launch_bounds__(256) void scan_k(const unsigned short* __restrict__ delta, // [NR,2048] bf16
                                              const unsigned short* __restrict__ u,     // [NR,2048] bf16
                                              const unsigned short* __restrict__ xdbl,  // [NR,256] bf16
                                              const unsigned short* __restrict__ xz,    // z at [.,2048+d]
                                              const float* __restrict__ A_log,          // [2048,64]
                                              const float* __restrict__ Dp,             // [2048]
                                              unsigned short* __restrict__ yg) {        // [NR,2048] bf16
  const int tid = threadIdx.x;
  const int lane = tid & 63, w = tid >> 6;
  const int wg = blockIdx.x;           // 0..1023
  const int b = wg >> 8;
  const int dblk = wg & 255;
  const int d0 = dblk * 8 + w * 2;
  const int n = lane;

  const float a0 = -__expf(A_log[(size_t)d0 * 64 + n]) * LOG2E;
  const float a1 = -__expf(A_log[(size_t)(d0 + 1) * 64 + n]) * LOG2E;
  float h0 = 0.f, h1 = 0.f;
  const float Dd = (lane < 2) ? Dp[d0 + lane] : 0.f;
  const size_t rb = (size_t)b * L_;

  for (int l = 0; l < L_; ++l) {
    size_t r = rb + l;
    unsigned int dd = *(const unsigned int*)(delta + r * 2048 + d0);
    unsigned int uu = *(const unsigned int*)(u + r * 2048 + d0);
    float dl0 = bf2f(dd & 0xffff), dl1 = bf2f(dd >> 16);
    float u0 = bf2f(uu & 0xffff), u1 = bf2f(uu >> 16);
    float Bn = bf2f(xdbl[r * 256 + 64 + n]);
    float Cn = bf2f(xdbl[r * 256 + 128 + n]);

    float dA0 = exp2f(dl0 * a0);
    h0 = dA0 * h0 + (dl0 * u0) * Bn;
    float p0 = h0 * Cn;
    float dA1 = exp2f(dl1 * a1);
    h1 = dA1 * h1 + (dl1 * u1) * Bn;
    float p1 = h1 * Cn;

    #pragma unroll
    for (int m = 1; m < 64; m <<= 1) {
      p0 += __shfl_xor(p0, m, 64);
      p1 += __shfl_xor(p1, m, 64);
    }
    if (lane < 2) {
      float ys = lane ? p1 : p0;
      float ud = lane ? u1 : u0;
      int d = d0 + lane;
      float z = bf2f(xz[r * 4096 + 2048 + d]);
      float g = z / (1.f + __expf(-z));
      float yv = (ys + ud * Dd) * g;
      yg[r * 2048 + d] = f2bf(yv);
    }
  }
}

extern "C" void kernel_launch(void* const* d_in, const int* in_sizes, int n_in,
                              void* d_out, int out_size, void* d_ws, size_t ws_size,
                              hipStream_t stream) {
  const float* x         = (const float*)d_in[0];
  const float* norm_w    = (const float*)d_in[1];
  const float* in_proj_w = (const float*)d_in[2];
  const float* conv_w    = (const float*)d_in[3];
  const float* conv_b    = (const float*)d_in[4];
  const float* x_proj_w  = (const float*)d_in[5];
  const float* dt_proj_w = (const float*)d_in[6];
  const float* dt_proj_b = (const float*)d_in[7];
  const float* A_log     = (const float*)d_in[8];
  const float* Dp        = (const float*)d_in[9];
  const float* out_proj_w= (const float*)d_in[10];

  char* ws = (char*)d_ws;
  size_t off = 0;
  auto alloc = [&](size_t bytes) {
    char* p = ws + off;
    off += (bytes + 255) & ~(size_t)255;
    return p;
  };
  unsigned short* w_in  = (unsigned short*)alloc((size_t)4096 * 1024 * 2);
  unsigned short* w_xp  = (unsigned short*)alloc((size_t)NPAD * 2048 * 2);
  unsigned short* w_dt  = (unsigned short*)alloc((size_t)2048 * 64 * 2);
  unsigned short* w_out = (unsigned short*)alloc((size_t)1024 * 2048 * 2);
  unsigned short* xn    = (unsigned short*)alloc((size_t)NR * 1024 * 2);
  unsigned short* xz    = (unsigned short*)alloc((size_t)NR * 4096 * 2);
  unsigned short* u     = (unsigned short*)alloc((size_t)NR * 2048 * 2);
  unsigned short* xdbl  = (unsigned short*)alloc((size_t)NR * 256 * 2);
  unsigned short* delta = (unsigned short*)alloc((size_t)NR * 2048 * 2);
  unsigned short* yg    = (unsigned short*)alloc((size_t)NR * 2048 * 2);
  if (ws_size < off) return;  // workspace too small -> fail loudly via validation

  // weight conversions
  cvt_k<<<4096, 256, 0, stream>>>(in_proj_w, w_in, 1048576);
  cvt_k<<<128, 256, 0, stream>>>(dt_proj_w, w_dt, 32768);
  cvt_k<<<2048, 256, 0, stream>>>(out_proj_w, w_out, 524288);
  cvt_pad_xp<<<2048, 256, 0, stream>>>(x_proj_w, w_xp);

  // 1. RMSNorm
  rmsnorm_k<<<NR, 256, 0, stream>>>(x, norm_w, xn);

  // 2. in_proj: xz = xn @ in_proj_w^T  [8192 x 4096]
  gemm_bt<0><<<dim3(4096 / 128, NR / 128), 256, 0, stream>>>(
      xn, w_in, xz, nullptr, NR, 4096, 1024, 1024, 1024, 4096);

  // 3. conv1d + SiLU -> u
  conv_silu_k<<<dim3(8, 16, 4), 256, 0, stream>>>(xz, conv_w, conv_b, u);

  // 4. x_proj: xdbl = u @ x_proj_w^T (padded to 256 cols)
  gemm_bt<0><<<dim3(NPAD / 128, NR / 128), 256, 0, stream>>>(
      u, w_xp, xdbl, nullptr, NR, NPAD, 2048, 2048, 2048, NPAD);

  // 5. delta = softplus(dt @ dt_proj_w^T + dt_proj_b)
  gemm_bt<1><<<dim3(2048 / 128, NR / 128), 256, 0, stream>>>(
      xdbl, w_dt, delta, dt_proj_b, NR, 2048, 64, NPAD, 64, 2048);

  // 6. selective scan + gate -> yg
  scan_k<<<1024, 256, 0, stream>>>(delta, u, xdbl, xz, A_log, Dp, yg);

  // 7. out = yg @ out_proj_w^T + x
  gemm_bt<2><<<dim3(1024 / 128, NR / 128), 256, 0, stream>>>(
      yg, w_out, d_out, x, NR, 1024, 2048, 2048, 2048, 1024);
}

// Round 2
// 1287.486 us; speedup vs baseline: 1.6942x; 1.6942x over previous
//
#include <hip/hip_runtime.h>
#include <hip/hip_bf16.h>
#include <stdint.h>
#include <math.h>

#define B_   4
#define L_   2048
#define DM   1024
#define DI   2048
#define NR   (B_*L_)   // 8192 rows
#define NST  64
#define NPAD 256       // padded x_proj rows (192 real)
#define LOG2E 1.44269504088896340736f

typedef __attribute__((ext_vector_type(8))) short bf16x8;
typedef __attribute__((ext_vector_type(4))) float f32x4;

__device__ __forceinline__ float bf2f(unsigned short u) {
  union { unsigned int i; float f; } v; v.i = ((unsigned int)u) << 16; return v.f;
}
__device__ __forceinline__ unsigned short f2bf(float f) {
  union { float f; unsigned int i; } v; v.f = f;
  unsigned int r = v.i + 0x7fff + ((v.i >> 16) & 1);
  return (unsigned short)(r >> 16);
}

__device__ __forceinline__ void gload_lds16(const void* g, void* l) {
  __builtin_amdgcn_global_load_lds(
      (const __attribute__((address_space(1))) void*)g,
      (__attribute__((address_space(3))) void*)l, 16, 0, 0);
}

// ---------- weight conversion ----------
__global__ __launch_bounds__(256) void cvt_k(const float* __restrict__ s,
                                             unsigned short* __restrict__ d, int nq) {
  int i = blockIdx.x * 256 + threadIdx.x;
  if (i < nq) {
    float4 v = ((const float4*)s)[i];
    ushort4 o;
    o.x = f2bf(v.x); o.y = f2bf(v.y); o.z = f2bf(v.z); o.w = f2bf(v.w);
    ((ushort4*)d)[i] = o;
  }
}

__global__ __launch_bounds__(256) void cvt_pad_xp(const float* __restrict__ s,
                                                  unsigned short* __restrict__ d) {
  int idx = blockIdx.x * 256 + threadIdx.x;   // over 256*2048
  int row = idx >> 11, col = idx & 2047;
  float v = (row < 192) ? s[row * 2048 + col] : 0.f;
  d[idx] = f2bf(v);
}

// ---------- RMSNorm (f32 in -> bf16 out) ----------
__global__ __launch_bounds__(256) void rmsnorm_k(const float* __restrict__ x,
                                                 const float* __restrict__ w,
                                                 unsigned short* __restrict__ xn) {
  int row = blockIdx.x;
  int t = threadIdx.x;
  float4 v = ((const float4*)(x + (size_t)row * DM))[t];
  float ss = v.x*v.x + v.y*v.y + v.z*v.z + v.w*v.w;
  #pragma unroll
  for (int m = 1; m < 64; m <<= 1) ss += __shfl_xor(ss, m, 64);
  __shared__ float s4[4];
  if ((t & 63) == 0) s4[t >> 6] = ss;
  __syncthreads();
  float tot = s4[0] + s4[1] + s4[2] + s4[3];
  float scale = rsqrtf(tot * (1.0f / DM) + 1e-6f);
  float4 wv = ((const float4*)w)[t];
  ushort4 o;
  o.x = f2bf(v.x * scale * wv.x);
  o.y = f2bf(v.y * scale * wv.y);
  o.z = f2bf(v.z * scale * wv.z);
  o.w = f2bf(v.w * scale * wv.w);
  ((ushort4*)(xn + (size_t)row * DM))[t] = o;
}

// ---------- bf16 MFMA GEMM: C[M,N] = A[M,K] * W[N,K]^T ----------
// EPI 0: bf16 store; 1: softplus(acc + aux[col]) bf16 store; 2: acc + auxF32[idx] f32 store
template<int EPI>
__global__ __launch_bounds__(256)
void gemm_bt(const unsigned short* __restrict__ A,
             const unsigned short* __restrict__ W,
             void* __restrict__ C, const float* __restrict__ aux,
             int M, int N, int K, int lda, int ldb, int ldc)
{
  __shared__ unsigned short lA[128 * 32];
  __shared__ unsigned short lB[128 * 32];
  const int tid = threadIdx.x;
  const int lane = tid & 63, w = tid >> 6;
  const int brow = blockIdx.y * 128, bcol = blockIdx.x * 128;
  const int wr = w >> 1, wc = w & 1;

  f32x4 acc[4][4];
  #pragma unroll
  for (int m = 0; m < 4; ++m)
    #pragma unroll
    for (int n = 0; n < 4; ++n) acc[m][n] = (f32x4){0.f, 0.f, 0.f, 0.f};

  const int srow = w * 32 + (lane >> 2);
  const int scol = (lane & 3) * 8;
  const unsigned short* gA = A + (size_t)(brow + srow) * lda + scol;
  const unsigned short* gB = W + (size_t)(bcol + srow) * ldb + scol;
  unsigned short* sA = lA + (w * 32) * 32;
  unsigned short* sB = lB + (w * 32) * 32;

  const int ka = (lane >> 4) * 8;
  const int ra = lane & 15;

  for (int k0 = 0; k0 < K; k0 += 32) {
    gload_lds16(gA + k0,                sA);
    gload_lds16(gA + k0 + 16 * lda,     sA + 16 * 32);
    gload_lds16(gB + k0,                sB);
    gload_lds16(gB + k0 + 16 * ldb,     sB + 16 * 32);
    __syncthreads();
    bf16x8 af[4], bfr[4];
    #pragma unroll
    for (int m = 0; m < 4; ++m)
      af[m] = *(const bf16x8*)(lA + (wr * 64 + m * 16 + ra) * 32 + ka);
    #pragma unroll
    for (int n = 0; n < 4; ++n)
      bfr[n] = *(const bf16x8*)(lB + (wc * 64 + n * 16 + ra) * 32 + ka);
    #pragma unroll
    for (int m = 0; m < 4; ++m)
      #pragma unroll
      for (int n = 0; n < 4; ++n)
        acc[m][n] = __builtin_amdgcn_mfma_f32_16x16x32_bf16(af[m], bfr[n], acc[m][n], 0, 0, 0);
    __syncthreads();
  }

  const int fq = lane >> 4;
  #pragma unroll
  for (int m = 0; m < 4; ++m) {
    #pragma unroll
    for (int n = 0; n < 4; ++n) {
      #pragma unroll
      for (int j = 0; j < 4; ++j) {
        int r = brow + wr * 64 + m * 16 + fq * 4 + j;
        int c = bcol + wc * 64 + n * 16 + ra;
        size_t idx = (size_t)r * ldc + c;
        float v = acc[m][n][j];
        if (EPI == 0) {
          ((unsigned short*)C)[idx] = f2bf(v);
        } else if (EPI == 1) {
          v += aux[c];
          v = (v > 20.f) ? v : log1pf(__expf(v));
          ((unsigned short*)C)[idx] = f2bf(v);
        } else {
          ((float*)C)[idx] = v + aux[idx];
        }
      }
    }
  }
}

// ---------- causal depthwise conv1d + SiLU ----------
__global__ __launch_bounds__(256) void conv_silu_k(const unsigned short* __restrict__ xz,
                                                   const float* __restrict__ cw,
                                                   const float* __restrict__ cb,
                                                   unsigned short* __restrict__ u) {
  int d = blockIdx.x * 256 + threadIdx.x;   // 0..2047
  int b = blockIdx.z;
  int l0 = blockIdx.y * 128;
  float w0 = cw[d * 4 + 0], w1 = cw[d * 4 + 1], w2 = cw[d * 4 + 2], w3 = cw[d * 4 + 3];
  float bias = cb[d];
  float xm3 = 0.f, xm2 = 0.f, xm1 = 0.f;
  size_t rb = (size_t)b * L_;
  if (l0 > 0) {
    xm3 = bf2f(xz[(rb + l0 - 3) * 4096 + d]);
    xm2 = bf2f(xz[(rb + l0 - 2) * 4096 + d]);
    xm1 = bf2f(xz[(rb + l0 - 1) * 4096 + d]);
  }
  for (int l = l0; l < l0 + 128; ++l) {
    float xc = bf2f(xz[(rb + l) * 4096 + d]);
    float v = w0 * xm3 + w1 * xm2 + w2 * xm1 + w3 * xc + bias;
    float s = v / (1.f + __expf(-v));
    u[(rb + l) * 2048 + d] = f2bf(s);
    xm3 = xm2; xm2 = xm1; xm1 = xc;
  }
}

// ---------- selective scan + gate ----------
// wave = 4 channels x 64 states. lane: d = d0 + (lane>>4), states nb..nb+3, nb=(lane&15)*4.
// y-reduction: 4-level shfl_xor over the 16-lane channel group. Explicit next-step prefetch.
__global__ __launch_bounds__(256) void scan_k(const unsigned short* __restrict__ delta, // [NR,2048] bf16
                                              const unsigned short* __restrict__ u,     // [NR,2048] bf16
                                              const unsigned short* __restrict__ xdbl,  // [NR,256] bf16
                                              const unsigned short* __restrict__ xz,    // z at [.,2048+d]
                                              const float* __restrict__ A_log,          // [2048,64]
                                              const float* __restrict__ Dp,             // [2048]
                                              unsigned short* __restrict__ yg) {        // [NR,2048] bf16
  const int tid = threadIdx.x;
  const int lane = tid & 63, w = tid >> 6;
  const int blk = blockIdx.x;            // 512 blocks: b(2b) x dblk(128)
  const int b = blk >> 7;
  const int dblk = blk & 127;
  const int d = dblk * 16 + w * 4 + (lane >> 4);
  const int nb = (lane & 15) * 4;

  float4 av = *(const float4*)(A_log + (size_t)d * 64 + nb);
  const float a0 = -__expf(av.x) * LOG2E;
  const float a1 = -__expf(av.y) * LOG2E;
  const float a2 = -__expf(av.z) * LOG2E;
  const float a3 = -__expf(av.w) * LOG2E;
  float h0 = 0.f, h1 = 0.f, h2 = 0.f, h3 = 0.f;
  const float Dd = Dp[d];
  const size_t rb = (size_t)b * L_;

  // prefetch step 0
  size_t r0 = rb;
  unsigned short dl_c = delta[r0 * 2048 + d];
  unsigned short uu_c = u[r0 * 2048 + d];
  ushort4 B_c = *(const ushort4*)(xdbl + r0 * 256 + 64 + nb);
  ushort4 C_c = *(const ushort4*)(xdbl + r0 * 256 + 128 + nb);
  unsigned short z_c = xz[r0 * 4096 + 2048 + d];

  for (int l = 0; l < L_; ++l) {
    // issue next-step loads (clamped) — independent of compute below
    size_t rn = rb + (l + 1 < L_ ? l + 1 : l);
    unsigned short dl_n = delta[rn * 2048 + d];
    unsigned short uu_n = u[rn * 2048 + d];
    ushort4 B_n = *(const ushort4*)(xdbl + rn * 256 + 64 + nb);
    ushort4 C_n = *(const ushort4*)(xdbl + rn * 256 + 128 + nb);
    unsigned short z_n = xz[rn * 4096 + 2048 + d];

    float dl = bf2f(dl_c), uv = bf2f(uu_c);
    float du = dl * uv;
    float y;
    { float dA = exp2f(dl * a0); h0 = dA * h0 + du * bf2f(B_c.x); y  = h0 * bf2f(C_c.x); }
    { float dA = exp2f(dl * a1); h1 = dA * h1 + du * bf2f(B_c.y); y += h1 * bf2f(C_c.y); }
    { float dA = exp2f(dl * a2); h2 = dA * h2 + du * bf2f(B_c.z); y += h2 * bf2f(C_c.z); }
    { float dA = exp2f(dl * a3); h3 = dA * h3 + du * bf2f(B_c.w); y += h3 * bf2f(C_c.w); }

    y += __shfl_xor(y, 1, 64);
    y += __shfl_xor(y, 2, 64);
    y += __shfl_xor(y, 4, 64);
    y += __shfl_xor(y, 8, 64);

    if ((lane & 15) == 0) {
      float z = bf2f(z_c);
      float g = z / (1.f + __expf(-z));
      float yv = (y + uv * Dd) * g;
      yg[(rb + l) * 2048 + d] = f2bf(yv);
    }

    dl_c = dl_n; uu_c = uu_n; B_c = B_n; C_c = C_n; z_c = z_n;
  }
}

extern "C" void kernel_launch(void* const* d_in, const int* in_sizes, int n_in,
                              void* d_out, int out_size, void* d_ws, size_t ws_size,
                              hipStream_t stream) {
  const float* x         = (const float*)d_in[0];
  const float* norm_w    = (const float*)d_in[1];
  const float* in_proj_w = (const float*)d_in[2];
  const float* conv_w    = (const float*)d_in[3];
  const float* conv_b    = (const float*)d_in[4];
  const float* x_proj_w  = (const float*)d_in[5];
  const float* dt_proj_w = (const float*)d_in[6];
  const float* dt_proj_b = (const float*)d_in[7];
  const float* A_log     = (const float*)d_in[8];
  const float* Dp        = (const float*)d_in[9];
  const float* out_proj_w= (const float*)d_in[10];

  char* ws = (char*)d_ws;
  size_t off = 0;
  auto alloc = [&](size_t bytes) {
    char* p = ws + off;
    off += (bytes + 255) & ~(size_t)255;
    return p;
  };
  unsigned short* w_in  = (unsigned short*)alloc((size_t)4096 * 1024 * 2);
  unsigned short* w_xp  = (unsigned short*)alloc((size_t)NPAD * 2048 * 2);
  unsigned short* w_dt  = (unsigned short*)alloc((size_t)2048 * 64 * 2);
  unsigned short* w_out = (unsigned short*)alloc((size_t)1024 * 2048 * 2);
  unsigned short* xn    = (unsigned short*)alloc((size_t)NR * 1024 * 2);
  unsigned short* xz    = (unsigned short*)alloc((size_t)NR * 4096 * 2);
  unsigned short* u     = (unsigned short*)alloc((size_t)NR * 2048 * 2);
  unsigned short* xdbl  = (unsigned short*)alloc((size_t)NR * 256 * 2);
  unsigned short* delta = (unsigned short*)alloc((size_t)NR * 2048 * 2);
  unsigned short* yg    = (unsigned short*)alloc((size_t)NR * 2048 * 2);
  if (ws_size < off) return;

  // weight conversions
  cvt_k<<<4096, 256, 0, stream>>>(in_proj_w, w_in, 1048576);
  cvt_k<<<128, 256, 0, stream>>>(dt_proj_w, w_dt, 32768);
  cvt_k<<<2048, 256, 0, stream>>>(out_proj_w, w_out, 524288);
  cvt_pad_xp<<<2048, 256, 0, stream>>>(x_proj_w, w_xp);

  // 1. RMSNorm
  rmsnorm_k<<<NR, 256, 0, stream>>>(x, norm_w, xn);

  // 2. in_proj: xz = xn @ in_proj_w^T  [8192 x 4096]
  gemm_bt<0><<<dim3(4096 / 128, NR / 128), 256, 0, stream>>>(
      xn, w_in, xz, nullptr, NR, 4096, 1024, 1024, 1024, 4096);

  // 3. conv1d + SiLU -> u
  conv_silu_k<<<dim3(8, 16, 4), 256, 0, stream>>>(xz, conv_w, conv_b, u);

  // 4. x_proj: xdbl = u @ x_proj_w^T (padded to 256 cols)
  gemm_bt<0><<<dim3(NPAD / 128, NR / 128), 256, 0, stream>>>(
      u, w_xp, xdbl, nullptr, NR, NPAD, 2048, 2048, 2048, NPAD);

  // 5. delta = softplus(dt @ dt_proj_w^T + dt_proj_b)
  gemm_bt<1><<<dim3(2048 / 128, NR / 128), 256, 0, stream>>>(
      xdbl, w_dt, delta, dt_proj_b, NR, 2048, 64, NPAD, 64, 2048);

  // 6. selective scan + gate -> yg
  scan_k<<<512, 256, 0, stream>>>(delta, u, xdbl, xz, A_log, Dp, yg);

  // 7. out = yg @ out_proj_w^T + x
  gemm_bt<2><<<dim3(1024 / 128, NR / 128), 256, 0, stream>>>(
      yg, w_out, d_out, x, NR, 1024, 2048, 2048, 2048, 1024);
}

// Round 3
// 1197.692 us; speedup vs baseline: 1.8212x; 1.0750x over previous
//
#include <hip/hip_runtime.h>
#include <hip/hip_bf16.h>
#include <stdint.h>
#include <math.h>

#define B_   4
#define L_   2048
#define DM   1024
#define DI   2048
#define NR   (B_*L_)   // 8192 rows
#define NST  64
#define NPAD 256       // padded x_proj rows (192 real)
#define NCH  8         // scan chunks
#define CL   256       // chunk length
#define LOG2E 1.44269504088896340736f

typedef __attribute__((ext_vector_type(8))) short bf16x8;
typedef __attribute__((ext_vector_type(4))) float f32x4;

__device__ __forceinline__ float bf2f(unsigned short u) {
  union { unsigned int i; float f; } v; v.i = ((unsigned int)u) << 16; return v.f;
}
__device__ __forceinline__ unsigned short f2bf(float f) {
  union { float f; unsigned int i; } v; v.f = f;
  unsigned int r = v.i + 0x7fff + ((v.i >> 16) & 1);
  return (unsigned short)(r >> 16);
}

__device__ __forceinline__ void gload_lds16(const void* g, void* l) {
  __builtin_amdgcn_global_load_lds(
      (const __attribute__((address_space(1))) void*)g,
      (__attribute__((address_space(3))) void*)l, 16, 0, 0);
}

// ---------- weight conversion ----------
__global__ __launch_bounds__(256) void cvt_k(const float* __restrict__ s,
                                             unsigned short* __restrict__ d, int nq) {
  int i = blockIdx.x * 256 + threadIdx.x;
  if (i < nq) {
    float4 v = ((const float4*)s)[i];
    ushort4 o;
    o.x = f2bf(v.x); o.y = f2bf(v.y); o.z = f2bf(v.z); o.w = f2bf(v.w);
    ((ushort4*)d)[i] = o;
  }
}

__global__ __launch_bounds__(256) void cvt_pad_xp(const float* __restrict__ s,
                                                  unsigned short* __restrict__ d) {
  int idx = blockIdx.x * 256 + threadIdx.x;   // over 256*2048
  int row = idx >> 11, col = idx & 2047;
  float v = (row < 192) ? s[row * 2048 + col] : 0.f;
  d[idx] = f2bf(v);
}

// ---------- RMSNorm (f32 in -> bf16 out) ----------
__global__ __launch_bounds__(256) void rmsnorm_k(const float* __restrict__ x,
                                                 const float* __restrict__ w,
                                                 unsigned short* __restrict__ xn) {
  int row = blockIdx.x;
  int t = threadIdx.x;
  float4 v = ((const float4*)(x + (size_t)row * DM))[t];
  float ss = v.x*v.x + v.y*v.y + v.z*v.z + v.w*v.w;
  #pragma unroll
  for (int m = 1; m < 64; m <<= 1) ss += __shfl_xor(ss, m, 64);
  __shared__ float s4[4];
  if ((t & 63) == 0) s4[t >> 6] = ss;
  __syncthreads();
  float tot = s4[0] + s4[1] + s4[2] + s4[3];
  float scale = rsqrtf(tot * (1.0f / DM) + 1e-6f);
  float4 wv = ((const float4*)w)[t];
  ushort4 o;
  o.x = f2bf(v.x * scale * wv.x);
  o.y = f2bf(v.y * scale * wv.y);
  o.z = f2bf(v.z * scale * wv.z);
  o.w = f2bf(v.w * scale * wv.w);
  ((ushort4*)(xn + (size_t)row * DM))[t] = o;
}

// ---------- bf16 MFMA GEMM: C[M,N] = A[M,K] * W[N,K]^T ----------
// EPI 0: bf16 store; 1: softplus(acc + aux[col]) bf16 store; 2: acc + auxF32[idx] f32 store
template<int EPI>
__global__ __launch_bounds__(256)
void gemm_bt(const unsigned short* __restrict__ A,
             const unsigned short* __restrict__ W,
             void* __restrict__ C, const float* __restrict__ aux,
             int M, int N, int K, int lda, int ldb, int ldc)
{
  __shared__ unsigned short lA[128 * 32];
  __shared__ unsigned short lB[128 * 32];
  const int tid = threadIdx.x;
  const int lane = tid & 63, w = tid >> 6;
  const int brow = blockIdx.y * 128, bcol = blockIdx.x * 128;
  const int wr = w >> 1, wc = w & 1;

  f32x4 acc[4][4];
  #pragma unroll
  for (int m = 0; m < 4; ++m)
    #pragma unroll
    for (int n = 0; n < 4; ++n) acc[m][n] = (f32x4){0.f, 0.f, 0.f, 0.f};

  const int srow = w * 32 + (lane >> 2);
  const int scol = (lane & 3) * 8;
  const unsigned short* gA = A + (size_t)(brow + srow) * lda + scol;
  const unsigned short* gB = W + (size_t)(bcol + srow) * ldb + scol;
  unsigned short* sA = lA + (w * 32) * 32;
  unsigned short* sB = lB + (w * 32) * 32;

  const int ka = (lane >> 4) * 8;
  const int ra = lane & 15;

  for (int k0 = 0; k0 < K; k0 += 32) {
    gload_lds16(gA + k0,                sA);
    gload_lds16(gA + k0 + 16 * lda,     sA + 16 * 32);
    gload_lds16(gB + k0,                sB);
    gload_lds16(gB + k0 + 16 * ldb,     sB + 16 * 32);
    __syncthreads();
    bf16x8 af[4], bfr[4];
    #pragma unroll
    for (int m = 0; m < 4; ++m)
      af[m] = *(const bf16x8*)(lA + (wr * 64 + m * 16 + ra) * 32 + ka);
    #pragma unroll
    for (int n = 0; n < 4; ++n)
      bfr[n] = *(const bf16x8*)(lB + (wc * 64 + n * 16 + ra) * 32 + ka);
    #pragma unroll
    for (int m = 0; m < 4; ++m)
      #pragma unroll
      for (int n = 0; n < 4; ++n)
        acc[m][n] = __builtin_amdgcn_mfma_f32_16x16x32_bf16(af[m], bfr[n], acc[m][n], 0, 0, 0);
    __syncthreads();
  }

  const int fq = lane >> 4;
  #pragma unroll
  for (int m = 0; m < 4; ++m) {
    #pragma unroll
    for (int n = 0; n < 4; ++n) {
      #pragma unroll
      for (int j = 0; j < 4; ++j) {
        int r = brow + wr * 64 + m * 16 + fq * 4 + j;
        int c = bcol + wc * 64 + n * 16 + ra;
        size_t idx = (size_t)r * ldc + c;
        float v = acc[m][n][j];
        if (EPI == 0) {
          ((unsigned short*)C)[idx] = f2bf(v);
        } else if (EPI == 1) {
          v += aux[c];
          v = (v > 20.f) ? v : log1pf(__expf(v));
          ((unsigned short*)C)[idx] = f2bf(v);
        } else {
          ((float*)C)[idx] = v + aux[idx];
        }
      }
    }
  }
}

// ---------- causal depthwise conv1d + SiLU ----------
__global__ __launch_bounds__(256) void conv_silu_k(const unsigned short* __restrict__ xz,
                                                   const float* __restrict__ cw,
                                                   const float* __restrict__ cb,
                                                   unsigned short* __restrict__ u) {
  int d = blockIdx.x * 256 + threadIdx.x;   // 0..2047
  int b = blockIdx.z;
  int l0 = blockIdx.y * 128;
  float w0 = cw[d * 4 + 0], w1 = cw[d * 4 + 1], w2 = cw[d * 4 + 2], w3 = cw[d * 4 + 3];
  float bias = cb[d];
  float xm3 = 0.f, xm2 = 0.f, xm1 = 0.f;
  size_t rb = (size_t)b * L_;
  if (l0 > 0) {
    xm3 = bf2f(xz[(rb + l0 - 3) * 4096 + d]);
    xm2 = bf2f(xz[(rb + l0 - 2) * 4096 + d]);
    xm1 = bf2f(xz[(rb + l0 - 1) * 4096 + d]);
  }
  for (int l = l0; l < l0 + 128; ++l) {
    float xc = bf2f(xz[(rb + l) * 4096 + d]);
    float v = w0 * xm3 + w1 * xm2 + w2 * xm1 + w3 * xc + bias;
    float s = v / (1.f + __expf(-v));
    u[(rb + l) * 2048 + d] = f2bf(s);
    xm3 = xm2; xm2 = xm1; xm1 = xc;
  }
}

// ---------- chunked selective scan ----------
// Decomposition: h_l = dA_l h_{l-1} + dBu_l is affine ->
//   over chunk c: h_end = (prod dA) * h_start + h_local(from 0).
// pass1: per-chunk local scan from 0 -> P (prod dA), q (final local h)
// pass2: inter-chunk scan of (P,q) -> h_start per chunk
// pass3: per-chunk full scan from h_start, with y-reduce + gate + store.
// Wave layout (pass1/3): 4 channels x 64 states; lane: d-sub = lane>>4,
// states nb..nb+3, nb=(lane&15)*4. Blocks: b(4) x chunk(8) x dblk(128).

__global__ __launch_bounds__(256, 8) void scan1_k(const unsigned short* __restrict__ delta,
                                                  const unsigned short* __restrict__ u,
                                                  const unsigned short* __restrict__ xdbl,
                                                  const float* __restrict__ A_log,
                                                  float* __restrict__ Pq,   // [B_*NCH][2048][64]
                                                  float* __restrict__ hq) { // [B_*NCH][2048][64]
  const int tid = threadIdx.x;
  const int lane = tid & 63, w = tid >> 6;
  const int blk = blockIdx.x;            // 4096
  const int b = blk >> 10;
  const int c = (blk >> 7) & 7;
  const int dblk = blk & 127;
  const int d = dblk * 16 + w * 4 + (lane >> 4);
  const int nb = (lane & 15) * 4;

  float4 av = *(const float4*)(A_log + (size_t)d * 64 + nb);
  const float a0 = -__expf(av.x) * LOG2E;
  const float a1 = -__expf(av.y) * LOG2E;
  const float a2 = -__expf(av.z) * LOG2E;
  const float a3 = -__expf(av.w) * LOG2E;
  float h0 = 0.f, h1 = 0.f, h2 = 0.f, h3 = 0.f;
  float P0 = 1.f, P1 = 1.f, P2 = 1.f, P3 = 1.f;
  const size_t rb = (size_t)b * L_ + (size_t)c * CL;

  unsigned short dl_c = delta[rb * 2048 + d];
  unsigned short uu_c = u[rb * 2048 + d];
  ushort4 B_c = *(const ushort4*)(xdbl + rb * 256 + 64 + nb);

  for (int l = 0; l < CL; ++l) {
    size_t rn = rb + (l + 1 < CL ? l + 1 : l);
    unsigned short dl_n = delta[rn * 2048 + d];
    unsigned short uu_n = u[rn * 2048 + d];
    ushort4 B_n = *(const ushort4*)(xdbl + rn * 256 + 64 + nb);

    float dl = bf2f(dl_c), uv = bf2f(uu_c);
    float du = dl * uv;
    { float dA = exp2f(dl * a0); h0 = dA * h0 + du * bf2f(B_c.x); P0 *= dA; }
    { float dA = exp2f(dl * a1); h1 = dA * h1 + du * bf2f(B_c.y); P1 *= dA; }
    { float dA = exp2f(dl * a2); h2 = dA * h2 + du * bf2f(B_c.z); P2 *= dA; }
    { float dA = exp2f(dl * a3); h3 = dA * h3 + du * bf2f(B_c.w); P3 *= dA; }

    dl_c = dl_n; uu_c = uu_n; B_c = B_n;
  }

  size_t o = (((size_t)(b * NCH + c)) * 2048 + d) * 64 + nb;
  *(float4*)(Pq + o) = (float4){P0, P1, P2, P3};
  *(float4*)(hq + o) = (float4){h0, h1, h2, h3};
}

__global__ __launch_bounds__(256) void scan2_k(const float* __restrict__ Pq,
                                               const float* __restrict__ hq,
                                               float* __restrict__ hst) { // [B_*NCH][2048][64]
  // one thread per (b,d,n); scan over chunks
  int g = blockIdx.x * 256 + threadIdx.x;   // 524288
  int b = g >> 17;
  int dn = g & 131071;                       // d*64+n
  float hs = 0.f;
  size_t base = ((size_t)b * NCH) * 131072 + dn;
  hst[base] = 0.f;
  #pragma unroll
  for (int c = 0; c < NCH - 1; ++c) {
    size_t o = base + (size_t)c * 131072;
    hs = Pq[o] * hs + hq[o];
    hst[o + 131072] = hs;
  }
}

__global__ __launch_bounds__(256, 8) void scan3_k(const unsigned short* __restrict__ delta,
                                                  const unsigned short* __restrict__ u,
                                                  const unsigned short* __restrict__ xdbl,
                                                  const unsigned short* __restrict__ xz,
                                                  const float* __restrict__ A_log,
                                                  const float* __restrict__ Dp,
                                                  const float* __restrict__ hst,
                                                  unsigned short* __restrict__ yg) {
  const int tid = threadIdx.x;
  const int lane = tid & 63, w = tid >> 6;
  const int blk = blockIdx.x;            // 4096
  const int b = blk >> 10;
  const int c = (blk >> 7) & 7;
  const int dblk = blk & 127;
  const int d = dblk * 16 + w * 4 + (lane >> 4);
  const int nb = (lane & 15) * 4;

  float4 av = *(const float4*)(A_log + (size_t)d * 64 + nb);
  const float a0 = -__expf(av.x) * LOG2E;
  const float a1 = -__expf(av.y) * LOG2E;
  const float a2 = -__expf(av.z) * LOG2E;
  const float a3 = -__expf(av.w) * LOG2E;
  float4 h0v = *(const float4*)(hst + (((size_t)(b * NCH + c)) * 2048 + d) * 64 + nb);
  float h0 = h0v.x, h1 = h0v.y, h2 = h0v.z, h3 = h0v.w;
  const float Dd = Dp[d];
  const size_t rb = (size_t)b * L_ + (size_t)c * CL;

  unsigned short dl_c = delta[rb * 2048 + d];
  unsigned short uu_c = u[rb * 2048 + d];
  ushort4 B_c = *(const ushort4*)(xdbl + rb * 256 + 64 + nb);
  ushort4 C_c = *(const ushort4*)(xdbl + rb * 256 + 128 + nb);
  unsigned short z_c = xz[rb * 4096 + 2048 + d];

  for (int l = 0; l < CL; ++l) {
    size_t rn = rb + (l + 1 < CL ? l + 1 : l);
    unsigned short dl_n = delta[rn * 2048 + d];
    unsigned short uu_n = u[rn * 2048 + d];
    ushort4 B_n = *(const ushort4*)(xdbl + rn * 256 + 64 + nb);
    ushort4 C_n = *(const ushort4*)(xdbl + rn * 256 + 128 + nb);
    unsigned short z_n = xz[rn * 4096 + 2048 + d];

    float dl = bf2f(dl_c), uv = bf2f(uu_c);
    float du = dl * uv;
    float y;
    { float dA = exp2f(dl * a0); h0 = dA * h0 + du * bf2f(B_c.x); y  = h0 * bf2f(C_c.x); }
    { float dA = exp2f(dl * a1); h1 = dA * h1 + du * bf2f(B_c.y); y += h1 * bf2f(C_c.y); }
    { float dA = exp2f(dl * a2); h2 = dA * h2 + du * bf2f(B_c.z); y += h2 * bf2f(C_c.z); }
    { float dA = exp2f(dl * a3); h3 = dA * h3 + du * bf2f(B_c.w); y += h3 * bf2f(C_c.w); }

    y += __shfl_xor(y, 1, 64);
    y += __shfl_xor(y, 2, 64);
    y += __shfl_xor(y, 4, 64);
    y += __shfl_xor(y, 8, 64);

    if ((lane & 15) == 0) {
      float z = bf2f(z_c);
      float g = z / (1.f + __expf(-z));
      float yv = (y + uv * Dd) * g;
      yg[(rb + l) * 2048 + d] = f2bf(yv);
    }

    dl_c = dl_n; uu_c = uu_n; B_c = B_n; C_c = C_n; z_c = z_n;
  }
}

extern "C" void kernel_launch(void* const* d_in, const int* in_sizes, int n_in,
                              void* d_out, int out_size, void* d_ws, size_t ws_size,
                              hipStream_t stream) {
  const float* x         = (const float*)d_in[0];
  const float* norm_w    = (const float*)d_in[1];
  const float* in_proj_w = (const float*)d_in[2];
  const float* conv_w    = (const float*)d_in[3];
  const float* conv_b    = (const float*)d_in[4];
  const float* x_proj_w  = (const float*)d_in[5];
  const float* dt_proj_w = (const float*)d_in[6];
  const float* dt_proj_b = (const float*)d_in[7];
  const float* A_log     = (const float*)d_in[8];
  const float* Dp        = (const float*)d_in[9];
  const float* out_proj_w= (const float*)d_in[10];

  char* ws = (char*)d_ws;
  size_t off = 0;
  auto alloc = [&](size_t bytes) {
    char* p = ws + off;
    off += (bytes + 255) & ~(size_t)255;
    return p;
  };
  unsigned short* w_in  = (unsigned short*)alloc((size_t)4096 * 1024 * 2);
  unsigned short* w_xp  = (unsigned short*)alloc((size_t)NPAD * 2048 * 2);
  unsigned short* w_dt  = (unsigned short*)alloc((size_t)2048 * 64 * 2);
  unsigned short* w_out = (unsigned short*)alloc((size_t)1024 * 2048 * 2);
  unsigned short* xn    = (unsigned short*)alloc((size_t)NR * 1024 * 2);
  unsigned short* xz    = (unsigned short*)alloc((size_t)NR * 4096 * 2);
  unsigned short* u     = (unsigned short*)alloc((size_t)NR * 2048 * 2);
  unsigned short* xdbl  = (unsigned short*)alloc((size_t)NR * 256 * 2);
  unsigned short* delta = (unsigned short*)alloc((size_t)NR * 2048 * 2);
  unsigned short* yg    = (unsigned short*)alloc((size_t)NR * 2048 * 2);
  float* Pq  = (float*)alloc((size_t)B_ * NCH * 2048 * 64 * 4);
  float* hq  = (float*)alloc((size_t)B_ * NCH * 2048 * 64 * 4);
  float* hst = (float*)alloc((size_t)B_ * NCH * 2048 * 64 * 4);
  if (ws_size < off) return;

  // weight conversions
  cvt_k<<<4096, 256, 0, stream>>>(in_proj_w, w_in, 1048576);
  cvt_k<<<128, 256, 0, stream>>>(dt_proj_w, w_dt, 32768);
  cvt_k<<<2048, 256, 0, stream>>>(out_proj_w, w_out, 524288);
  cvt_pad_xp<<<2048, 256, 0, stream>>>(x_proj_w, w_xp);

  // 1. RMSNorm
  rmsnorm_k<<<NR, 256, 0, stream>>>(x, norm_w, xn);

  // 2. in_proj: xz = xn @ in_proj_w^T  [8192 x 4096]
  gemm_bt<0><<<dim3(4096 / 128, NR / 128), 256, 0, stream>>>(
      xn, w_in, xz, nullptr, NR, 4096, 1024, 1024, 1024, 4096);

  // 3. conv1d + SiLU -> u
  conv_silu_k<<<dim3(8, 16, 4), 256, 0, stream>>>(xz, conv_w, conv_b, u);

  // 4. x_proj: xdbl = u @ x_proj_w^T (padded to 256 cols)
  gemm_bt<0><<<dim3(NPAD / 128, NR / 128), 256, 0, stream>>>(
      u, w_xp, xdbl, nullptr, NR, NPAD, 2048, 2048, 2048, NPAD);

  // 5. delta = softplus(dt @ dt_proj_w^T + dt_proj_b)
  gemm_bt<1><<<dim3(2048 / 128, NR / 128), 256, 0, stream>>>(
      xdbl, w_dt, delta, dt_proj_b, NR, 2048, 64, NPAD, 64, 2048);

  // 6. chunked selective scan + gate -> yg
  scan1_k<<<4096, 256, 0, stream>>>(delta, u, xdbl, A_log, Pq, hq);
  scan2_k<<<2048, 256, 0, stream>>>(Pq, hq, hst);
  scan3_k<<<4096, 256, 0, stream>>>(delta, u, xdbl, xz, A_log, Dp, hst, yg);

  // 7. out = yg @ out_proj_w^T + x
  gemm_bt<2><<<dim3(1024 / 128, NR / 128), 256, 0, stream>>>(
      yg, w_out, d_out, x, NR, 1024, 2048, 2048, 2048, 1024);
}

// Round 5
// 745.605 us; speedup vs baseline: 2.9255x; 1.6063x over previous
//
#include <hip/hip_runtime.h>
#include <hip/hip_bf16.h>
#include <stdint.h>
#include <math.h>

#define B_   4
#define L_   2048
#define DM   1024
#define DI   2048
#define NR   (B_*L_)   // 8192 rows
#define NPAD 256       // padded x_proj rows (192 real)
#define NCH  8         // scan chunks
#define CL   256       // chunk length
#define LOG2E 1.44269504088896340736f
#define LN2   0.69314718055994530942f

typedef __attribute__((ext_vector_type(8))) short bf16x8;
typedef __attribute__((ext_vector_type(4))) float f32x4;

__device__ __forceinline__ float bf2f(unsigned short u) {
  union { unsigned int i; float f; } v; v.i = ((unsigned int)u) << 16; return v.f;
}
__device__ __forceinline__ unsigned short f2bf(float f) {
  union { float f; unsigned int i; } v; v.f = f;
  unsigned int r = v.i + 0x7fff + ((v.i >> 16) & 1);
  return (unsigned short)(r >> 16);
}

__device__ __forceinline__ float fexp2(float x) {
#if __has_builtin(__builtin_amdgcn_exp2f)
  return __builtin_amdgcn_exp2f(x);
#else
  float r; asm("v_exp_f32 %0, %1" : "=v"(r) : "v"(x)); return r;
#endif
}
__device__ __forceinline__ float frcp(float x) {
#if __has_builtin(__builtin_amdgcn_rcpf)
  return __builtin_amdgcn_rcpf(x);
#else
  float r; asm("v_rcp_f32 %0, %1" : "=v"(r) : "v"(x)); return r;
#endif
}
__device__ __forceinline__ float flog2(float x) {
#if __has_builtin(__builtin_amdgcn_logf)
  return __builtin_amdgcn_logf(x);
#else
  float r; asm("v_log_f32 %0, %1" : "=v"(r) : "v"(x)); return r;
#endif
}
__device__ __forceinline__ float fsilu(float z) {
  return z * frcp(1.f + fexp2(-z * LOG2E));
}
__device__ __forceinline__ unsigned int cvtpk(float lo, float hi) {
  unsigned int r;
  asm("v_cvt_pk_bf16_f32 %0, %1, %2" : "=v"(r) : "v"(lo), "v"(hi));
  return r;
}

__device__ __forceinline__ void gload_lds16(const void* g, void* l) {
  __builtin_amdgcn_global_load_lds(
      (const __attribute__((address_space(1))) void*)g,
      (__attribute__((address_space(3))) void*)l, 16, 0, 0);
}

// ---------- weight conversion ----------
__global__ __launch_bounds__(256) void cvt_k(const float* __restrict__ s,
                                             unsigned short* __restrict__ d, int nq) {
  int i = blockIdx.x * 256 + threadIdx.x;
  if (i < nq) {
    float4 v = ((const float4*)s)[i];
    ushort4 o;
    o.x = f2bf(v.x); o.y = f2bf(v.y); o.z = f2bf(v.z); o.w = f2bf(v.w);
    ((ushort4*)d)[i] = o;
  }
}

__global__ __launch_bounds__(256) void cvt_pad_xp(const float* __restrict__ s,
                                                  unsigned short* __restrict__ d) {
  int idx = blockIdx.x * 256 + threadIdx.x;
  int row = idx >> 11, col = idx & 2047;
  float v = (row < 192) ? s[row * 2048 + col] : 0.f;
  d[idx] = f2bf(v);
}

// ---------- RMSNorm ----------
__global__ __launch_bounds__(256) void rmsnorm_k(const float* __restrict__ x,
                                                 const float* __restrict__ w,
                                                 unsigned short* __restrict__ xn) {
  int row = blockIdx.x;
  int t = threadIdx.x;
  float4 v = ((const float4*)(x + (size_t)row * DM))[t];
  float ss = v.x*v.x + v.y*v.y + v.z*v.z + v.w*v.w;
  #pragma unroll
  for (int m = 1; m < 64; m <<= 1) ss += __shfl_xor(ss, m, 64);
  __shared__ float s4[4];
  if ((t & 63) == 0) s4[t >> 6] = ss;
  __syncthreads();
  float tot = s4[0] + s4[1] + s4[2] + s4[3];
  float scale = rsqrtf(tot * (1.0f / DM) + 1e-6f);
  float4 wv = ((const float4*)w)[t];
  ushort4 o;
  o.x = f2bf(v.x * scale * wv.x);
  o.y = f2bf(v.y * scale * wv.y);
  o.z = f2bf(v.z * scale * wv.z);
  o.w = f2bf(v.w * scale * wv.w);
  ((ushort4*)(xn + (size_t)row * DM))[t] = o;
}

// ---------- bf16 MFMA GEMM: C[M,N] = A[M,K] * W[N,K]^T ----------
// EPI 0: bf16 store (SPLIT: col<2048 -> C, else C2, both ld 2048)
// EPI 1: softplus(acc + aux[col]) bf16 ; EPI 2: acc + auxF32[idx] f32
template<int EPI, int SPLIT>
__global__ __launch_bounds__(256)
void gemm_bt(const unsigned short* __restrict__ A,
             const unsigned short* __restrict__ W,
             void* __restrict__ C, void* __restrict__ C2,
             const float* __restrict__ aux,
             int M, int N, int K, int lda, int ldb, int ldc)
{
  __shared__ unsigned short lA[128 * 32];
  __shared__ unsigned short lB[128 * 32];
  const int tid = threadIdx.x;
  const int lane = tid & 63, w = tid >> 6;
  const int brow = blockIdx.y * 128, bcol = blockIdx.x * 128;
  const int wr = w >> 1, wc = w & 1;

  f32x4 acc[4][4];
  #pragma unroll
  for (int m = 0; m < 4; ++m)
    #pragma unroll
    for (int n = 0; n < 4; ++n) acc[m][n] = (f32x4){0.f, 0.f, 0.f, 0.f};

  const int srow = w * 32 + (lane >> 2);
  const int scol = (lane & 3) * 8;
  const unsigned short* gA = A + (size_t)(brow + srow) * lda + scol;
  const unsigned short* gB = W + (size_t)(bcol + srow) * ldb + scol;
  unsigned short* sA = lA + (w * 32) * 32;
  unsigned short* sB = lB + (w * 32) * 32;

  const int ka = (lane >> 4) * 8;
  const int ra = lane & 15;

  for (int k0 = 0; k0 < K; k0 += 32) {
    gload_lds16(gA + k0,                sA);
    gload_lds16(gA + k0 + 16 * lda,     sA + 16 * 32);
    gload_lds16(gB + k0,                sB);
    gload_lds16(gB + k0 + 16 * ldb,     sB + 16 * 32);
    __syncthreads();
    bf16x8 af[4], bfr[4];
    #pragma unroll
    for (int m = 0; m < 4; ++m)
      af[m] = *(const bf16x8*)(lA + (wr * 64 + m * 16 + ra) * 32 + ka);
    #pragma unroll
    for (int n = 0; n < 4; ++n)
      bfr[n] = *(const bf16x8*)(lB + (wc * 64 + n * 16 + ra) * 32 + ka);
    #pragma unroll
    for (int m = 0; m < 4; ++m)
      #pragma unroll
      for (int n = 0; n < 4; ++n)
        acc[m][n] = __builtin_amdgcn_mfma_f32_16x16x32_bf16(af[m], bfr[n], acc[m][n], 0, 0, 0);
    __syncthreads();
  }

  void* Cb = C;
  int cb = bcol;
  if (SPLIT) { if (bcol >= 2048) Cb = C2; cb = bcol & 2047; }

  const int fq = lane >> 4;
  #pragma unroll
  for (int m = 0; m < 4; ++m) {
    #pragma unroll
    for (int n = 0; n < 4; ++n) {
      #pragma unroll
      for (int j = 0; j < 4; ++j) {
        int r = brow + wr * 64 + m * 16 + fq * 4 + j;
        int c = cb + wc * 64 + n * 16 + ra;
        size_t idx = (size_t)r * ldc + c;
        float v = acc[m][n][j];
        if (EPI == 0) {
          ((unsigned short*)Cb)[idx] = f2bf(v);
        } else if (EPI == 1) {
          v += aux[c];
          v = (v > 20.f) ? v : flog2(1.f + fexp2(v * LOG2E)) * LN2;
          ((unsigned short*)Cb)[idx] = f2bf(v);
        } else {
          ((float*)Cb)[idx] = v + aux[idx];
        }
      }
    }
  }
}

// ---------- causal depthwise conv1d + SiLU ----------
__global__ __launch_bounds__(256) void conv_silu_k(const unsigned short* __restrict__ x_in,
                                                   const float* __restrict__ cw,
                                                   const float* __restrict__ cb,
                                                   unsigned short* __restrict__ u) {
  int d = blockIdx.x * 256 + threadIdx.x;
  int b = blockIdx.z;
  int l0 = blockIdx.y * 128;
  float w0 = cw[d * 4 + 0], w1 = cw[d * 4 + 1], w2 = cw[d * 4 + 2], w3 = cw[d * 4 + 3];
  float bias = cb[d];
  float xm3 = 0.f, xm2 = 0.f, xm1 = 0.f;
  size_t rb = (size_t)b * L_;
  if (l0 > 0) {
    xm3 = bf2f(x_in[(rb + l0 - 3) * 2048 + d]);
    xm2 = bf2f(x_in[(rb + l0 - 2) * 2048 + d]);
    xm1 = bf2f(x_in[(rb + l0 - 1) * 2048 + d]);
  }
  for (int l = l0; l < l0 + 128; ++l) {
    float xc = bf2f(x_in[(rb + l) * 2048 + d]);
    float v = w0 * xm3 + w1 * xm2 + w2 * xm1 + w3 * xc + bias;
    u[(rb + l) * 2048 + d] = f2bf(fsilu(v));
    xm3 = xm2; xm2 = xm1; xm1 = xc;
  }
}

// ---------- transpose delta,u -> dT,uT [2048 d][8192 bl] ----------
__global__ __launch_bounds__(256) void trans_du_k(const unsigned short* __restrict__ delta,
                                                  const unsigned short* __restrict__ u,
                                                  unsigned short* __restrict__ dT,
                                                  unsigned short* __restrict__ uT) {
  __shared__ unsigned short t_lds[64][72];
  const int t = threadIdx.x;
  const int d0 = blockIdx.x * 64, r0 = blockIdx.y * 64;
  const unsigned short* src = blockIdx.z ? u : delta;
  unsigned short* dst = blockIdx.z ? uT : dT;
  #pragma unroll
  for (int i = 0; i < 4; ++i) {
    int r = (t >> 4) + i * 16, c4 = (t & 15) * 4;
    ushort4 v = *(const ushort4*)(src + (size_t)(r0 + r) * 2048 + d0 + c4);
    t_lds[c4 + 0][r] = v.x; t_lds[c4 + 1][r] = v.y;
    t_lds[c4 + 2][r] = v.z; t_lds[c4 + 3][r] = v.w;
  }
  __syncthreads();
  #pragma unroll
  for (int i = 0; i < 4; ++i) {
    int dr = (t >> 4) + i * 16, rc = (t & 15) * 4;
    ushort4 v = *(const ushort4*)&t_lds[dr][rc];
    *(ushort4*)(dst + (size_t)(d0 + dr) * 8192 + r0 + rc) = v;
  }
}

// ---------- convert xdbl B,C columns to f32 (with zero pad row 8192) ----------
__global__ __launch_bounds__(128) void cvt_bc_k(const unsigned short* __restrict__ xdbl,
                                                float* __restrict__ Bf, float* __restrict__ Cf) {
  int row = blockIdx.x;   // 0..8192 (8192 = pad)
  int t = threadIdx.x;    // 0..127
  float v = 0.f;
  if (row < NR) v = bf2f(xdbl[(size_t)row * 256 + 64 + t]);
  if (t < 64) Bf[(size_t)row * 64 + t] = v;
  else        Cf[(size_t)row * 64 + (t - 64)] = v;
}

// ---------- chunked selective scan ----------
// wave = 4 channels x 64 states; d = dblk*16 + w*4 + (lane>>4); nb=(lane&15)*4
// pass1 -> hq (local final h) + sd (sum of delta per chunk; P = exp2(a*sd))
__global__ __launch_bounds__(256, 8) void scan1_k(const unsigned short* __restrict__ dT,
                                                  const unsigned short* __restrict__ uT,
                                                  const float* __restrict__ Bf,
                                                  const float* __restrict__ A_log,
                                                  float* __restrict__ sdb,   // [B_*NCH][2048]
                                                  float* __restrict__ hq) {  // [B_*NCH][2048][64]
  const int tid = threadIdx.x;
  const int lane = tid & 63, w = tid >> 6;
  const int blk = blockIdx.x;            // 4096
  const int b = blk >> 10;
  const int c = (blk >> 7) & 7;
  const int dblk = blk & 127;
  const int d = dblk * 16 + w * 4 + (lane >> 4);
  const int nb = (lane & 15) * 4;

  float4 av = *(const float4*)(A_log + (size_t)d * 64 + nb);
  const float a0 = -__expf(av.x) * LOG2E;
  const float a1 = -__expf(av.y) * LOG2E;
  const float a2 = -__expf(av.z) * LOG2E;
  const float a3 = -__expf(av.w) * LOG2E;
  float h0 = 0.f, h1 = 0.f, h2 = 0.f, h3 = 0.f, sd = 0.f;

  const int col0 = b * 2048 + c * CL;
  const unsigned short* pD = dT + (size_t)d * 8192 + col0;
  const unsigned short* pU = uT + (size_t)d * 8192 + col0;
  const float* pBt = Bf + (size_t)col0 * 64 + nb;

  uint4 dpk = *(const uint4*)pD;
  uint4 upk = *(const uint4*)pU;
  float4 Bc = *(const float4*)pBt;

  for (int t = 0; t < CL / 8; ++t) {
    uint4 dpk_n = (t + 1 < CL / 8) ? *(const uint4*)(pD + (size_t)(t + 1) * 8) : dpk;
    uint4 upk_n = (t + 1 < CL / 8) ? *(const uint4*)(pU + (size_t)(t + 1) * 8) : upk;
    float dlv[8], uvv[8];
    {
      const unsigned int* pd = (const unsigned int*)&dpk;
      const unsigned int* pu = (const unsigned int*)&upk;
      #pragma unroll
      for (int q = 0; q < 4; ++q) {
        dlv[2*q]   = __uint_as_float(pd[q] << 16);
        dlv[2*q+1] = __uint_as_float(pd[q] & 0xffff0000u);
        uvv[2*q]   = __uint_as_float(pu[q] << 16);
        uvv[2*q+1] = __uint_as_float(pu[q] & 0xffff0000u);
      }
    }
    #pragma unroll
    for (int j = 0; j < 8; ++j) {
      float4 Bn = *(const float4*)(pBt + (j + 1) * 64);
      float dl = dlv[j], uv = uvv[j];
      sd += dl;
      float du = dl * uv;
      h0 = fmaf(fexp2(dl * a0), h0, du * Bc.x);
      h1 = fmaf(fexp2(dl * a1), h1, du * Bc.y);
      h2 = fmaf(fexp2(dl * a2), h2, du * Bc.z);
      h3 = fmaf(fexp2(dl * a3), h3, du * Bc.w);
      Bc = Bn;
    }
    pBt += 8 * 64;
    dpk = dpk_n; upk = upk_n;
  }

  size_t o = (((size_t)(b * NCH + c)) * 2048 + d) * 64 + nb;
  *(float4*)(hq + o) = (float4){h0, h1, h2, h3};
  if ((lane & 15) == 0) sdb[(size_t)(b * NCH + c) * 2048 + d] = sd;
}

__global__ __launch_bounds__(256) void scan2_k(const float* __restrict__ sdb,
                                               const float* __restrict__ hq,
                                               const float* __restrict__ A_log,
                                               float* __restrict__ hst) {
  int g = blockIdx.x * 256 + threadIdx.x;   // 524288
  int b = g >> 17;
  int dn = g & 131071;                       // d*64+n
  int d = dn >> 6;
  float a = -__expf(A_log[dn]) * LOG2E;
  float hs = 0.f;
  size_t base = ((size_t)b * NCH) * 131072 + dn;
  hst[base] = 0.f;
  #pragma unroll
  for (int c = 0; c < NCH - 1; ++c) {
    size_t o = base + (size_t)c * 131072;
    float P = fexp2(a * sdb[(size_t)(b * NCH + c) * 2048 + d]);
    hs = P * hs + hq[o];
    hst[o + 131072] = hs;
  }
}

__global__ __launch_bounds__(256, 6) void scan3_k(const unsigned short* __restrict__ dT,
                                                  const unsigned short* __restrict__ uT,
                                                  const float* __restrict__ Bf,
                                                  const float* __restrict__ Cf,
                                                  const float* __restrict__ A_log,
                                                  const float* __restrict__ hst,
                                                  unsigned short* __restrict__ yT) {
  __shared__ uint4 ylds4[4][4][32];   // [wave][ch][l/8]
  const int tid = threadIdx.x;
  const int lane = tid & 63, w = tid >> 6;
  const int blk = blockIdx.x;            // 4096
  const int b = blk >> 10;
  const int c = (blk >> 7) & 7;
  const int dblk = blk & 127;
  const int d = dblk * 16 + w * 4 + (lane >> 4);
  const int nb = (lane & 15) * 4;

  float4 av = *(const float4*)(A_log + (size_t)d * 64 + nb);
  const float a0 = -__expf(av.x) * LOG2E;
  const float a1 = -__expf(av.y) * LOG2E;
  const float a2 = -__expf(av.z) * LOG2E;
  const float a3 = -__expf(av.w) * LOG2E;
  float4 h0v = *(const float4*)(hst + (((size_t)(b * NCH + c)) * 2048 + d) * 64 + nb);
  float h0 = h0v.x, h1 = h0v.y, h2 = h0v.z, h3 = h0v.w;

  const int col0 = b * 2048 + c * CL;
  const unsigned short* pD = dT + (size_t)d * 8192 + col0;
  const unsigned short* pU = uT + (size_t)d * 8192 + col0;
  const float* pBt = Bf + (size_t)col0 * 64 + nb;
  const float* pCt = Cf + (size_t)col0 * 64 + nb;

  uint4 dpk = *(const uint4*)pD;
  uint4 upk = *(const uint4*)pU;
  float4 Bc = *(const float4*)pBt;
  float4 Cc = *(const float4*)pCt;

  for (int t = 0; t < CL / 8; ++t) {
    uint4 dpk_n = (t + 1 < CL / 8) ? *(const uint4*)(pD + (size_t)(t + 1) * 8) : dpk;
    uint4 upk_n = (t + 1 < CL / 8) ? *(const uint4*)(pU + (size_t)(t + 1) * 8) : upk;
    float dlv[8], uvv[8];
    {
      const unsigned int* pd = (const unsigned int*)&dpk;
      const unsigned int* pu = (const unsigned int*)&upk;
      #pragma unroll
      for (int q = 0; q < 4; ++q) {
        dlv[2*q]   = __uint_as_float(pd[q] << 16);
        dlv[2*q+1] = __uint_as_float(pd[q] & 0xffff0000u);
        uvv[2*q]   = __uint_as_float(pu[q] << 16);
        uvv[2*q+1] = __uint_as_float(pu[q] & 0xffff0000u);
      }
    }
    float yv[8];
    #pragma unroll
    for (int j = 0; j < 8; ++j) {
      float4 Bn = *(const float4*)(pBt + (j + 1) * 64);
      float4 Cn = *(const float4*)(pCt + (j + 1) * 64);
      float dl = dlv[j], uv = uvv[j];
      float du = dl * uv;
      float y;
      { h0 = fmaf(fexp2(dl * a0), h0, du * Bc.x); y  = h0 * Cc.x; }
      { h1 = fmaf(fexp2(dl * a1), h1, du * Bc.y); y = fmaf(h1, Cc.y, y); }
      { h2 = fmaf(fexp2(dl * a2), h2, du * Bc.z); y = fmaf(h2, Cc.z, y); }
      { h3 = fmaf(fexp2(dl * a3), h3, du * Bc.w); y = fmaf(h3, Cc.w, y); }
      y += __shfl_xor(y, 1);
      y += __shfl_xor(y, 2);
      y += __shfl_xor(y, 4);
      y += __shfl_xor(y, 8);
      yv[j] = y;
      Bc = Bn; Cc = Cn;
    }
    pBt += 8 * 64; pCt += 8 * 64;
    dpk = dpk_n; upk = upk_n;
    if ((lane & 15) == 0) {
      uint4 pk;
      pk.x = cvtpk(yv[0], yv[1]); pk.y = cvtpk(yv[2], yv[3]);
      pk.z = cvtpk(yv[4], yv[5]); pk.w = cvtpk(yv[6], yv[7]);
      ylds4[w][lane >> 4][t] = pk;
    }
  }

  const int dbase = dblk * 16 + w * 4;
  __builtin_amdgcn_s_waitcnt(0);  // drain LDS writes (wave-local)
  #pragma unroll
  for (int p = 0; p < 2; ++p) {
    int idx = p * 64 + lane;
    int ch = idx >> 5;
    int lc = idx & 31;
    uint4 v = ylds4[w][ch][lc];
    *(uint4*)(yT + (size_t)(dbase + ch) * 8192 + col0 + lc * 8) = v;
  }
}

// ---------- gate: yg[r][d] = (yT[d][r] + u*D) * silu(z), transposing ----------
__global__ __launch_bounds__(256) void gate_k(const unsigned short* __restrict__ yT,
                                              const unsigned short* __restrict__ u,
                                              const unsigned short* __restrict__ z,
                                              const float* __restrict__ Dp,
                                              unsigned short* __restrict__ yg) {
  __shared__ unsigned short g_lds[64][72];
  const int t = threadIdx.x;
  const int d0 = blockIdx.x * 64, r0 = blockIdx.y * 64;
  #pragma unroll
  for (int i = 0; i < 4; ++i) {
    int dr = (t >> 4) + i * 16, rc = (t & 15) * 4;
    ushort4 v = *(const ushort4*)(yT + (size_t)(d0 + dr) * 8192 + r0 + rc);
    g_lds[rc + 0][dr] = v.x; g_lds[rc + 1][dr] = v.y;
    g_lds[rc + 2][dr] = v.z; g_lds[rc + 3][dr] = v.w;
  }
  __syncthreads();
  int oc = (t & 15) * 4;
  float4 D4 = *(const float4*)(Dp + d0 + oc);
  #pragma unroll
  for (int i = 0; i < 4; ++i) {
    int orow = (t >> 4) + i * 16;
    ushort4 yv = *(const ushort4*)&g_lds[orow][oc];
    ushort4 uv = *(const ushort4*)(u + (size_t)(r0 + orow) * 2048 + d0 + oc);
    ushort4 zv = *(const ushort4*)(z + (size_t)(r0 + orow) * 2048 + d0 + oc);
    ushort4 o;
    o.x = f2bf((bf2f(yv.x) + bf2f(uv.x) * D4.x) * fsilu(bf2f(zv.x)));
    o.y = f2bf((bf2f(yv.y) + bf2f(uv.y) * D4.y) * fsilu(bf2f(zv.y)));
    o.z = f2bf((bf2f(yv.z) + bf2f(uv.z) * D4.z) * fsilu(bf2f(zv.z)));
    o.w = f2bf((bf2f(yv.w) + bf2f(uv.w) * D4.w) * fsilu(bf2f(zv.w)));
    *(ushort4*)(yg + (size_t)(r0 + orow) * 2048 + d0 + oc) = o;
  }
}

extern "C" void kernel_launch(void* const* d_in, const int* in_sizes, int n_in,
                              void* d_out, int out_size, void* d_ws, size_t ws_size,
                              hipStream_t stream) {
  const float* x         = (const float*)d_in[0];
  const float* norm_w    = (const float*)d_in[1];
  const float* in_proj_w = (const float*)d_in[2];
  const float* conv_w    = (const float*)d_in[3];
  const float* conv_b    = (const float*)d_in[4];
  const float* x_proj_w  = (const float*)d_in[5];
  const float* dt_proj_w = (const float*)d_in[6];
  const float* dt_proj_b = (const float*)d_in[7];
  const float* A_log     = (const float*)d_in[8];
  const float* Dp        = (const float*)d_in[9];
  const float* out_proj_w= (const float*)d_in[10];

  char* ws = (char*)d_ws;
  size_t off = 0;
  auto alloc = [&](size_t bytes) {
    char* p = ws + off;
    off += (bytes + 255) & ~(size_t)255;
    return p;
  };
  unsigned short* w_in  = (unsigned short*)alloc((size_t)4096 * 1024 * 2);   // 8MB
  unsigned short* w_xp  = (unsigned short*)alloc((size_t)NPAD * 2048 * 2);   // 1MB
  unsigned short* w_dt  = (unsigned short*)alloc((size_t)2048 * 64 * 2);     // .25MB
  unsigned short* w_out = (unsigned short*)alloc((size_t)1024 * 2048 * 2);   // 4MB
  unsigned short* xn    = (unsigned short*)alloc((size_t)NR * 1024 * 2);     // 16MB; later hst
  unsigned short* x_in  = (unsigned short*)alloc((size_t)NR * 2048 * 2);     // 32MB; later uT
  unsigned short* z     = (unsigned short*)alloc((size_t)NR * 2048 * 2);     // 32MB
  unsigned short* u     = (unsigned short*)alloc((size_t)NR * 2048 * 2);     // 32MB
  unsigned short* xdbl  = (unsigned short*)alloc((size_t)NR * 256 * 2);      // 4MB
  unsigned short* delta = (unsigned short*)alloc((size_t)NR * 2048 * 2);     // 32MB; later yT
  unsigned short* dT    = (unsigned short*)alloc((size_t)2048 * 8192 * 2);   // 32MB; later yg
  float* Bf  = (float*)alloc((size_t)(NR + 1) * 64 * 4);                     // 2.1MB
  float* Cf  = (float*)alloc((size_t)(NR + 1) * 64 * 4);                     // 2.1MB
  float* hq  = (float*)alloc((size_t)B_ * NCH * 2048 * 64 * 4);              // 16MB
  float* sdb = (float*)alloc((size_t)B_ * NCH * 2048 * 4);                   // .25MB
  if (ws_size < off) return;

  // aliases (lifetimes disjoint, stream-ordered)
  float* hst = (float*)xn;       // 16MB needed == 16MB xn; xn dead after in_proj
  unsigned short* uT = x_in;     // after conv, x_in dead
  unsigned short* yT = delta;    // after trans_du, delta dead
  unsigned short* yg = dT;       // after scan3, dT dead

  // weight conversions
  cvt_k<<<4096, 256, 0, stream>>>(in_proj_w, w_in, 1048576);
  cvt_k<<<128, 256, 0, stream>>>(dt_proj_w, w_dt, 32768);
  cvt_k<<<2048, 256, 0, stream>>>(out_proj_w, w_out, 524288);
  cvt_pad_xp<<<2048, 256, 0, stream>>>(x_proj_w, w_xp);

  // 1. RMSNorm
  rmsnorm_k<<<NR, 256, 0, stream>>>(x, norm_w, xn);

  // 2. in_proj -> x_in, z (split outputs)
  gemm_bt<0, 1><<<dim3(4096 / 128, NR / 128), 256, 0, stream>>>(
      xn, w_in, x_in, z, nullptr, NR, 4096, 1024, 1024, 1024, 2048);

  // 3. conv1d + SiLU -> u
  conv_silu_k<<<dim3(8, 16, 4), 256, 0, stream>>>(x_in, conv_w, conv_b, u);

  // 4. x_proj -> xdbl
  gemm_bt<0, 0><<<dim3(NPAD / 128, NR / 128), 256, 0, stream>>>(
      u, w_xp, xdbl, nullptr, nullptr, NR, NPAD, 2048, 2048, 2048, NPAD);

  // 5. delta = softplus(dt @ dt_proj_w^T + dt_proj_b)
  gemm_bt<1, 0><<<dim3(2048 / 128, NR / 128), 256, 0, stream>>>(
      xdbl, w_dt, delta, nullptr, dt_proj_b, NR, 2048, 64, NPAD, 64, 2048);

  // 6. scan prep: B/C f32 + transposes
  cvt_bc_k<<<NR + 1, 128, 0, stream>>>(xdbl, Bf, Cf);
  trans_du_k<<<dim3(32, 128, 2), 256, 0, stream>>>(delta, u, dT, uT);

  // 7. chunked selective scan
  scan1_k<<<4096, 256, 0, stream>>>(dT, uT, Bf, A_log, sdb, hq);
  scan2_k<<<2048, 256, 0, stream>>>(sdb, hq, A_log, hst);
  scan3_k<<<4096, 256, 0, stream>>>(dT, uT, Bf, Cf, A_log, hst, yT);

  // 8. gate + transpose back -> yg
  gate_k<<<dim3(32, 128), 256, 0, stream>>>(yT, u, z, Dp, yg);

  // 9. out = yg @ out_proj_w^T + x
  gemm_bt<2, 0><<<dim3(1024 / 128, NR / 128), 256, 0, stream>>>(
      yg, w_out, d_out, nullptr, x, NR, 1024, 2048, 2048, 2048, 1024);
}